// Round 18
// baseline (42.125 us; speedup 1.0000x reference)
//
#include <hip/hip_runtime.h>

#define N_ROWS 4096
#define D_DIM  512
#define ROWB   512              // bytes per i8 row
#define C_ROWS 8192
#define BM 256
#define BN 128
#define BKB 64                  // K-tile bytes = 64 i8 elems
#define NKT 8                   // 512 / 64
#define GXf (C_ROWS / BN)       // 64
#define GYf (N_ROWS / BM)       // 16
#define NBLK (GXf * GYf)        // 1024
#define NVALID 33550336.0f      // 4096 * 8191 (num_valid is provably constant)

typedef __attribute__((ext_vector_type(4))) int  i32x4;    // MFMA i8 frag/acc

#define AS1 __attribute__((address_space(1)))
#define AS3 __attribute__((address_space(3)))

__device__ __forceinline__ void gload_lds16(const void* g, void* l) {
    __builtin_amdgcn_global_load_lds((const AS1 unsigned int*)g,
                                     (AS3 unsigned int*)l, 16, 0, 0);
}

// ---------------- l2-normalize rows, fp32 -> i8 (q = round(127 x̂)) --------
__global__ __launch_bounds__(256) void normalize_kernel(
        const float* __restrict__ feat, const float* __restrict__ cent,
        unsigned char* __restrict__ fN, unsigned char* __restrict__ cN) {
    const int w    = threadIdx.x >> 6;
    const int lane = threadIdx.x & 63;
    const int row  = blockIdx.x * 4 + w;      // 0 .. 12287

    const float* src = (row < N_ROWS) ? feat + (size_t)row * D_DIM
                                      : cent + (size_t)(row - N_ROWS) * D_DIM;
    unsigned char* dst = (row < N_ROWS) ? fN + (size_t)row * ROWB
                                        : cN + (size_t)(row - N_ROWS) * ROWB;

    const float* r = src + lane * 8;
    float4 v0 = *(const float4*)(r);
    float4 v1 = *(const float4*)(r + 4);
    float ss = v0.x*v0.x + v0.y*v0.y + v0.z*v0.z + v0.w*v0.w
             + v1.x*v1.x + v1.y*v1.y + v1.z*v1.z + v1.w*v1.w;
    #pragma unroll
    for (int off = 32; off; off >>= 1) ss += __shfl_xor(ss, off);
    const float sc = 127.0f / fmaxf(sqrtf(ss), 1e-12f);

    int q0 = __float2int_rn(v0.x * sc), q1 = __float2int_rn(v0.y * sc);
    int q2 = __float2int_rn(v0.z * sc), q3 = __float2int_rn(v0.w * sc);
    int q4 = __float2int_rn(v1.x * sc), q5 = __float2int_rn(v1.y * sc);
    int q6 = __float2int_rn(v1.z * sc), q7 = __float2int_rn(v1.w * sc);

    uint2 o;
    o.x = (q0 & 0xFF) | ((q1 & 0xFF) << 8) | ((q2 & 0xFF) << 16) | ((q3 & 0xFF) << 24);
    o.y = (q4 & 0xFF) | ((q5 & 0xFF) << 8) | ((q6 & 0xFF) << 16) | ((q7 & 0xFF) << 24);
    *(uint2*)(dst + lane * 8) = o;
}

// ------------- pos_int[i] = fQ[i] . cQ[labels[i]]  (exact in fp32) ---------
__global__ __launch_bounds__(256) void posdot_kernel(
        const unsigned char* __restrict__ fN, const unsigned char* __restrict__ cN,
        const int* __restrict__ labels, float* __restrict__ pos) {
    const int w    = threadIdx.x >> 6;
    const int lane = threadIdx.x & 63;
    const int i    = blockIdx.x * 4 + w;
    const int lab  = labels[i];

    const uint2 a = *(const uint2*)(fN + (size_t)i   * ROWB + lane * 8);
    const uint2 b = *(const uint2*)(cN + (size_t)lab * ROWB + lane * 8);
    int s = 0;
    #pragma unroll
    for (int j = 0; j < 4; ++j) {
        s += (int)(signed char)((a.x >> (8 * j)) & 0xFF) *
             (int)(signed char)((b.x >> (8 * j)) & 0xFF);
        s += (int)(signed char)((a.y >> (8 * j)) & 0xFF) *
             (int)(signed char)((b.y >> (8 * j)) & 0xFF);
    }
    #pragma unroll
    for (int off = 32; off; off >>= 1) s += __shfl_xor(s, off);
    if (lane == 0) pos[i] = (float)s;    // |s| <= 8.3M < 2^24: exact
}

// ---------------- fused i8 GEMM + softplus reduction (NO mask) -------------
// R17 structure (triple-buffer single-barrier, vmcnt(3), setprio, exact-
// diagonal trick) plus:
//  - pos*k1 PRELOADED into 16 registers before the GEMM loop (latency hidden)
//  - LOG-OF-PRODUCTS epilogue: sum log2(1+2^x') = log2 prod(1+2^x');
//    4 parallel products of 16 terms each (max 10.2^16 = 1.4e16, safe in
//    fp32) -> 4 logs/thread instead of 64.  Diagonal's exact *2.0 factor is
//    preserved in the exponent; 4096 subtracted in finalize as before.
__global__ __launch_bounds__(512, 4) void fused_loss_kernel(
        const unsigned char* __restrict__ fN, const unsigned char* __restrict__ cN,
        const float* __restrict__ pos, float* __restrict__ partialL) {
    __shared__ __align__(16) unsigned char As[3][BM * BKB];   // 48 KB
    __shared__ __align__(16) unsigned char Bs[3][BN * BKB];   // 24 KB

    const int tid  = threadIdx.x;
    const int w    = tid >> 6;        // wave 0..7
    const int lane = tid & 63;
    const int wm   = w >> 1;          // 0..3  (M quarter: rows wm*64..+63)
    const int wn   = w & 1;           // 0..1  (N half:   cols wn*64..+63)

    // XCD-stripe mapping (bijective: 1024 = 8 xcd * 16 by * 8 c8)
    const int id  = blockIdx.x;       // 0..1023
    const int xcd = id & 7;
    const int loc = id >> 3;          // 0..127
    const int by  = loc & 15;         // inner: A rows sweep while B fixed
    const int c8  = loc >> 4;         // 0..7
    const int rowBase = by * BM;
    const int colBase = (xcd * 8 + c8) * BN;

    const int lr = lane & 15;
    const int kq = lane >> 4;         // 0..3 = 16B k-seg

    // preload pos*k1 for this thread's 16 output rows (hidden under GEMM)
    const float k1 = 1.44269504089e0f / 16129.0f;
    float pk[4][4];
    #pragma unroll
    for (int m = 0; m < 4; ++m)
        #pragma unroll
        for (int j = 0; j < 4; ++j)
            pk[m][j] = pos[rowBase + wm * 64 + m * 16 + kq * 4 + j] * k1;

    // staging: chunk = 16 rows x 64B; lane l -> row l>>2, LDS seg l&3,
    // fetching pre-swizzled global seg (l&3)^f(l>>2), f(x)=(x^(x>>2))&3
    const int gseg = ((lane & 3) ^ ((lane >> 2) & 3) ^ ((lane >> 4) & 3));
    const unsigned char* aG = fN + (size_t)(rowBase + w * 32 + (lane >> 2)) * ROWB + gseg * 16;
    const unsigned char* bG = cN + (size_t)(colBase + w * 16 + (lane >> 2)) * ROWB + gseg * 16;

#define STAGE(buf, t)                                                        \
    do {                                                                     \
        gload_lds16(aG + (t) * BKB,             &As[buf][(w * 32) * BKB]);   \
        gload_lds16(aG + (t) * BKB + 16 * ROWB, &As[buf][(w * 32 + 16) * BKB]); \
        gload_lds16(bG + (t) * BKB,             &Bs[buf][(w * 16) * BKB]);   \
    } while (0)

    // read: lane wants global seg kq (16 contiguous k) at row base+lr:
    // LDS seg = kq ^ f(lr)
    const int segrd = (lane ^ (lane >> 2) ^ (lane >> 4)) & 3;
    const int loff  = lr * BKB + segrd * 16;     // per-lane offset in tile

    i32x4 acc[4][4] = {};

    // prologue: tiles 0,1 in flight (6 loads/wave)
    STAGE(0, 0);
    STAGE(1, 1);

    #pragma unroll
    for (int t = 0; t < NKT; ++t) {
        const int cur = t % 3;
        // outstanding per wave here: [tile t: 3, tile t+1: 3] ->
        // vmcnt(3) retires exactly tile t (issued 2 iters ago: ~no stall).
        if (t < NKT - 1) asm volatile("s_waitcnt vmcnt(3)" ::: "memory");
        else             asm volatile("s_waitcnt vmcnt(0)" ::: "memory");
        __builtin_amdgcn_s_barrier();    // publishes tile t's LDS + proves all
                                         // waves done reading buf[(t+2)%3]
        if (t + 2 < NKT) STAGE((t + 2) % 3, t + 2);

        i32x4 af[4], bb[4];
        #pragma unroll
        for (int m = 0; m < 4; ++m)
            af[m] = *(const i32x4*)&As[cur][(wm * 64 + m * 16) * BKB + loff];
        #pragma unroll
        for (int n = 0; n < 4; ++n)
            bb[n] = *(const i32x4*)&Bs[cur][(wn * 64 + n * 16) * BKB + loff];

        // compiler emits counted lgkmcnt between reads and consuming MFMAs.
        __builtin_amdgcn_s_setprio(1);
        #pragma unroll
        for (int m = 0; m < 4; ++m)
            #pragma unroll
            for (int n = 0; n < 4; ++n)
                acc[m][n] = __builtin_amdgcn_mfma_i32_16x16x64_i8(
                                af[m], bb[n], acc[m][n], 0, 0, 0);
        __builtin_amdgcn_s_setprio(0);
    }
#undef STAGE

    // ---- epilogue: log-of-products (4 parallel, 16 terms each) ------------
    float pr0 = 1.0f, pr1 = 1.0f, pr2 = 1.0f, pr3 = 1.0f;
    #pragma unroll
    for (int m = 0; m < 4; ++m) {
        #pragma unroll
        for (int j = 0; j < 4; ++j) {
            const float p = pk[m][j];
            pr0 *= 1.0f + __builtin_amdgcn_exp2f(fmaf((float)acc[m][0][j], k1, -p));
            pr1 *= 1.0f + __builtin_amdgcn_exp2f(fmaf((float)acc[m][1][j], k1, -p));
            pr2 *= 1.0f + __builtin_amdgcn_exp2f(fmaf((float)acc[m][2][j], k1, -p));
            pr3 *= 1.0f + __builtin_amdgcn_exp2f(fmaf((float)acc[m][3][j], k1, -p));
        }
    }
    float lsum = __builtin_amdgcn_logf(pr0) + __builtin_amdgcn_logf(pr1)
               + __builtin_amdgcn_logf(pr2) + __builtin_amdgcn_logf(pr3);
    #pragma unroll
    for (int off = 32; off; off >>= 1) lsum += __shfl_xor(lsum, off);

    __syncthreads();                        // safe to reuse LDS
    float* s_sum = (float*)&As[0][0];
    if (lane == 0) s_sum[w] = lsum;
    __syncthreads();
    if (tid == 0) {
        float L = 0.0f;
        #pragma unroll
        for (int i = 0; i < 8; ++i) L += s_sum[i];
        partialL[id] = L;
    }
}

// ---------------- finalize: reduce 1024 per-block partials ----------------
__global__ __launch_bounds__(256) void finalize_kernel(
        const float* __restrict__ partialL, float* __restrict__ out) {
    __shared__ float s_sum[4];
    const int w    = threadIdx.x >> 6;
    const int lane = threadIdx.x & 63;

    float s = 0.0f;
    for (int i = threadIdx.x; i < NBLK; i += 256) s += partialL[i];
    #pragma unroll
    for (int off = 32; off; off >>= 1) s += __shfl_xor(s, off);
    if (lane == 0) s_sum[w] = s;
    __syncthreads();
    if (threadIdx.x == 0)
        out[0] = (s_sum[0] + s_sum[1] + s_sum[2] + s_sum[3] - 4096.0f)
                 * (0.69314718056f / NVALID);    // drop exact diagonal, fold ln2
}

extern "C" void kernel_launch(void* const* d_in, const int* in_sizes, int n_in,
                              void* d_out, int out_size, void* d_ws, size_t ws_size,
                              hipStream_t stream) {
    const float* features = (const float*)d_in[0];   // [4096, 512]
    const float* centers  = (const float*)d_in[1];   // [8192, 512]
    const int*   labels   = (const int*)d_in[2];     // [4096]
    float* out = (float*)d_out;

    char* ws = (char*)d_ws;
    unsigned char* fN  = (unsigned char*)ws;                          // 2 MB
    unsigned char* cN  = (unsigned char*)(ws + (2u << 20));           // 4 MB
    float*         pos = (float*)(ws + (6u << 20));                   // 16 KB
    float*         partialL = (float*)(ws + (6u << 20) + (1u << 16)); // 4 KB

    normalize_kernel<<<(N_ROWS + C_ROWS) / 4, 256, 0, stream>>>(features, centers, fN, cN);
    posdot_kernel<<<N_ROWS / 4, 256, 0, stream>>>(fN, cN, labels, pos);

    fused_loss_kernel<<<NBLK, 512, 0, stream>>>(fN, cN, pos, partialL);

    finalize_kernel<<<1, 256, 0, stream>>>(partialL, out);
}

// Round 19
// 38.222 us; speedup vs baseline: 1.1021x; 1.1021x over previous
//
#include <hip/hip_runtime.h>

#define N_ROWS 4096
#define D_DIM  512
#define ROWB   512              // bytes per i8 row
#define C_ROWS 8192
#define BM 256
#define BN 128
#define BKB 64                  // K-tile bytes = 64 i8 elems
#define NKT 8                   // 512 / 64
#define GXf (C_ROWS / BN)       // 64
#define GYf (N_ROWS / BM)       // 16
#define NBLK (GXf * GYf)        // 1024
#define NVALID 33550336.0f      // 4096 * 8191 (num_valid is provably constant)

typedef __attribute__((ext_vector_type(4))) int  i32x4;    // MFMA i8 frag/acc

#define AS1 __attribute__((address_space(1)))
#define AS3 __attribute__((address_space(3)))

__device__ __forceinline__ void gload_lds16(const void* g, void* l) {
    __builtin_amdgcn_global_load_lds((const AS1 unsigned int*)g,
                                     (AS3 unsigned int*)l, 16, 0, 0);
}

// ---------------- l2-normalize rows, fp32 -> i8 (q = round(127 x̂)) --------
__global__ __launch_bounds__(256) void normalize_kernel(
        const float* __restrict__ feat, const float* __restrict__ cent,
        unsigned char* __restrict__ fN, unsigned char* __restrict__ cN) {
    const int w    = threadIdx.x >> 6;
    const int lane = threadIdx.x & 63;
    const int row  = blockIdx.x * 4 + w;      // 0 .. 12287

    const float* src = (row < N_ROWS) ? feat + (size_t)row * D_DIM
                                      : cent + (size_t)(row - N_ROWS) * D_DIM;
    unsigned char* dst = (row < N_ROWS) ? fN + (size_t)row * ROWB
                                        : cN + (size_t)(row - N_ROWS) * ROWB;

    const float* r = src + lane * 8;
    float4 v0 = *(const float4*)(r);
    float4 v1 = *(const float4*)(r + 4);
    float ss = v0.x*v0.x + v0.y*v0.y + v0.z*v0.z + v0.w*v0.w
             + v1.x*v1.x + v1.y*v1.y + v1.z*v1.z + v1.w*v1.w;
    #pragma unroll
    for (int off = 32; off; off >>= 1) ss += __shfl_xor(ss, off);
    const float sc = 127.0f / fmaxf(sqrtf(ss), 1e-12f);

    int q0 = __float2int_rn(v0.x * sc), q1 = __float2int_rn(v0.y * sc);
    int q2 = __float2int_rn(v0.z * sc), q3 = __float2int_rn(v0.w * sc);
    int q4 = __float2int_rn(v1.x * sc), q5 = __float2int_rn(v1.y * sc);
    int q6 = __float2int_rn(v1.z * sc), q7 = __float2int_rn(v1.w * sc);

    uint2 o;
    o.x = (q0 & 0xFF) | ((q1 & 0xFF) << 8) | ((q2 & 0xFF) << 16) | ((q3 & 0xFF) << 24);
    o.y = (q4 & 0xFF) | ((q5 & 0xFF) << 8) | ((q6 & 0xFF) << 16) | ((q7 & 0xFF) << 24);
    *(uint2*)(dst + lane * 8) = o;
}

// ------------- pos_int[i] = fQ[i] . cQ[labels[i]]  (exact in fp32) ---------
__global__ __launch_bounds__(256) void posdot_kernel(
        const unsigned char* __restrict__ fN, const unsigned char* __restrict__ cN,
        const int* __restrict__ labels, float* __restrict__ pos) {
    const int w    = threadIdx.x >> 6;
    const int lane = threadIdx.x & 63;
    const int i    = blockIdx.x * 4 + w;
    const int lab  = labels[i];

    const uint2 a = *(const uint2*)(fN + (size_t)i   * ROWB + lane * 8);
    const uint2 b = *(const uint2*)(cN + (size_t)lab * ROWB + lane * 8);
    int s = 0;
    #pragma unroll
    for (int j = 0; j < 4; ++j) {
        s += (int)(signed char)((a.x >> (8 * j)) & 0xFF) *
             (int)(signed char)((b.x >> (8 * j)) & 0xFF);
        s += (int)(signed char)((a.y >> (8 * j)) & 0xFF) *
             (int)(signed char)((b.y >> (8 * j)) & 0xFF);
    }
    #pragma unroll
    for (int off = 32; off; off >>= 1) s += __shfl_xor(s, off);
    if (lane == 0) pos[i] = (float)s;    // |s| <= 8.3M < 2^24: exact
}

// ---------------- fused i8 GEMM + softplus reduction (NO mask) -------------
// R15 structure (triple-buffer single-barrier, vmcnt(3), setprio, exp2-domain
// epilogue) with the EXACT-DIAGONAL trick: for j == label_i, S_int == pos_int
// exactly (identical integer dots) -> x' = 0 -> log2(1+2^0) = 1.0 exactly.
// So sum ALL terms unmasked and subtract 4096 x 1.0 in finalize.  Removes
// per-element gj/compare/select and all labels loads from this kernel.
// (R18's log-of-products + pk-preload REVERTED: it lengthened the serial
// exp2->mul dependency chains and regressed +2.4 us.)
__global__ __launch_bounds__(512, 4) void fused_loss_kernel(
        const unsigned char* __restrict__ fN, const unsigned char* __restrict__ cN,
        const float* __restrict__ pos, float* __restrict__ partialL) {
    __shared__ __align__(16) unsigned char As[3][BM * BKB];   // 48 KB
    __shared__ __align__(16) unsigned char Bs[3][BN * BKB];   // 24 KB

    const int tid  = threadIdx.x;
    const int w    = tid >> 6;        // wave 0..7
    const int lane = tid & 63;
    const int wm   = w >> 1;          // 0..3  (M quarter: rows wm*64..+63)
    const int wn   = w & 1;           // 0..1  (N half:   cols wn*64..+63)

    // XCD-stripe mapping (bijective: 1024 = 8 xcd * 16 by * 8 c8)
    const int id  = blockIdx.x;       // 0..1023
    const int xcd = id & 7;
    const int loc = id >> 3;          // 0..127
    const int by  = loc & 15;         // inner: A rows sweep while B fixed
    const int c8  = loc >> 4;         // 0..7
    const int rowBase = by * BM;
    const int colBase = (xcd * 8 + c8) * BN;

    const int lr = lane & 15;
    const int kq = lane >> 4;         // 0..3 = 16B k-seg

    // staging: chunk = 16 rows x 64B; lane l -> row l>>2, LDS seg l&3,
    // fetching pre-swizzled global seg (l&3)^f(l>>2), f(x)=(x^(x>>2))&3
    const int gseg = ((lane & 3) ^ ((lane >> 2) & 3) ^ ((lane >> 4) & 3));
    const unsigned char* aG = fN + (size_t)(rowBase + w * 32 + (lane >> 2)) * ROWB + gseg * 16;
    const unsigned char* bG = cN + (size_t)(colBase + w * 16 + (lane >> 2)) * ROWB + gseg * 16;

#define STAGE(buf, t)                                                        \
    do {                                                                     \
        gload_lds16(aG + (t) * BKB,             &As[buf][(w * 32) * BKB]);   \
        gload_lds16(aG + (t) * BKB + 16 * ROWB, &As[buf][(w * 32 + 16) * BKB]); \
        gload_lds16(bG + (t) * BKB,             &Bs[buf][(w * 16) * BKB]);   \
    } while (0)

    // read: lane wants global seg kq (16 contiguous k) at row base+lr:
    // LDS seg = kq ^ f(lr)
    const int segrd = (lane ^ (lane >> 2) ^ (lane >> 4)) & 3;
    const int loff  = lr * BKB + segrd * 16;     // per-lane offset in tile

    i32x4 acc[4][4] = {};

    // prologue: tiles 0,1 in flight (6 loads/wave)
    STAGE(0, 0);
    STAGE(1, 1);

    #pragma unroll
    for (int t = 0; t < NKT; ++t) {
        const int cur = t % 3;
        // outstanding per wave here: [tile t: 3, tile t+1: 3] ->
        // vmcnt(3) retires exactly tile t (issued 2 iters ago: ~no stall).
        if (t < NKT - 1) asm volatile("s_waitcnt vmcnt(3)" ::: "memory");
        else             asm volatile("s_waitcnt vmcnt(0)" ::: "memory");
        __builtin_amdgcn_s_barrier();    // publishes tile t's LDS + proves all
                                         // waves done reading buf[(t+2)%3]
        if (t + 2 < NKT) STAGE((t + 2) % 3, t + 2);

        i32x4 af[4], bb[4];
        #pragma unroll
        for (int m = 0; m < 4; ++m)
            af[m] = *(const i32x4*)&As[cur][(wm * 64 + m * 16) * BKB + loff];
        #pragma unroll
        for (int n = 0; n < 4; ++n)
            bb[n] = *(const i32x4*)&Bs[cur][(wn * 64 + n * 16) * BKB + loff];

        // compiler emits counted lgkmcnt between reads and consuming MFMAs.
        __builtin_amdgcn_s_setprio(1);
        #pragma unroll
        for (int m = 0; m < 4; ++m)
            #pragma unroll
            for (int n = 0; n < 4; ++n)
                acc[m][n] = __builtin_amdgcn_mfma_i32_16x16x64_i8(
                                af[m], bb[n], acc[m][n], 0, 0, 0);
        __builtin_amdgcn_s_setprio(0);
    }
#undef STAGE

    // ---- epilogue (exp2-domain, unmasked): x' = (S-p)*k1, k1=log2e/127^2 --
    // softplus/ln2 = log2(1 + 2^x'); diagonal terms contribute exactly 1.0
    // each and are subtracted (4096 total) in finalize.
    const float k1 = 1.44269504089e0f / 16129.0f;
    float lsum = 0.0f;
    #pragma unroll
    for (int m = 0; m < 4; ++m) {
        #pragma unroll
        for (int j = 0; j < 4; ++j) {
            const int gi  = rowBase + wm * 64 + m * 16 + kq * 4 + j;
            const float pk = pos[gi] * k1;       // hoisted out of n-loop
            #pragma unroll
            for (int n = 0; n < 4; ++n) {
                const float xp = fmaf((float)acc[m][n][j], k1, -pk);
                lsum += __builtin_amdgcn_logf(1.0f + __builtin_amdgcn_exp2f(xp));
            }
        }
    }
    #pragma unroll
    for (int off = 32; off; off >>= 1) lsum += __shfl_xor(lsum, off);

    __syncthreads();                        // safe to reuse LDS
    float* s_sum = (float*)&As[0][0];
    if (lane == 0) s_sum[w] = lsum;
    __syncthreads();
    if (tid == 0) {
        float L = 0.0f;
        #pragma unroll
        for (int i = 0; i < 8; ++i) L += s_sum[i];
        partialL[id] = L;
    }
}

// ---------------- finalize: reduce 1024 per-block partials ----------------
__global__ __launch_bounds__(256) void finalize_kernel(
        const float* __restrict__ partialL, float* __restrict__ out) {
    __shared__ float s_sum[4];
    const int w    = threadIdx.x >> 6;
    const int lane = threadIdx.x & 63;

    float s = 0.0f;
    for (int i = threadIdx.x; i < NBLK; i += 256) s += partialL[i];
    #pragma unroll
    for (int off = 32; off; off >>= 1) s += __shfl_xor(s, off);
    if (lane == 0) s_sum[w] = s;
    __syncthreads();
    if (threadIdx.x == 0)
        out[0] = (s_sum[0] + s_sum[1] + s_sum[2] + s_sum[3] - 4096.0f)
                 * (0.69314718056f / NVALID);    // drop exact diagonal, fold ln2
}

extern "C" void kernel_launch(void* const* d_in, const int* in_sizes, int n_in,
                              void* d_out, int out_size, void* d_ws, size_t ws_size,
                              hipStream_t stream) {
    const float* features = (const float*)d_in[0];   // [4096, 512]
    const float* centers  = (const float*)d_in[1];   // [8192, 512]
    const int*   labels   = (const int*)d_in[2];     // [4096]
    float* out = (float*)d_out;

    char* ws = (char*)d_ws;
    unsigned char* fN  = (unsigned char*)ws;                          // 2 MB
    unsigned char* cN  = (unsigned char*)(ws + (2u << 20));           // 4 MB
    float*         pos = (float*)(ws + (6u << 20));                   // 16 KB
    float*         partialL = (float*)(ws + (6u << 20) + (1u << 16)); // 4 KB

    normalize_kernel<<<(N_ROWS + C_ROWS) / 4, 256, 0, stream>>>(features, centers, fN, cN);
    posdot_kernel<<<N_ROWS / 4, 256, 0, stream>>>(fN, cN, labels, pos);

    fused_loss_kernel<<<NBLK, 512, 0, stream>>>(fN, cN, pos, partialL);

    finalize_kernel<<<1, 256, 0, stream>>>(partialL, out);
}